// Round 1
// baseline (716.888 us; speedup 1.0000x reference)
//
#include <hip/hip_runtime.h>
#include <hip/hip_bf16.h>

#define S_LEN  2048
#define BATCH  2
#define NH     16
#define HD     128
#define HIDDEN 2048
#define MROWS  (BATCH*S_LEN)   // 4096

typedef __attribute__((ext_vector_type(8))) short bf16x8;
typedef __attribute__((ext_vector_type(4))) float f32x4;

__device__ __forceinline__ float bf2f(short s) {
    union { float f; unsigned int u; } v;
    v.u = ((unsigned int)(unsigned short)s) << 16;
    return v.f;
}
__device__ __forceinline__ short f2bf(float f) {
    union { float f; unsigned int u; } v;
    v.f = f;
    unsigned int r = v.u + 0x7fffu + ((v.u >> 16) & 1u);   // RNE, inputs never NaN
    return (short)(r >> 16);
}
__device__ __forceinline__ f32x4 mfma16(bf16x8 a, bf16x8 b, f32x4 c) {
    return __builtin_amdgcn_mfma_f32_16x16x32_bf16(a, b, c, 0, 0, 0);
}
__device__ __forceinline__ void gload16(const void* g, void* l) {
    __builtin_amdgcn_global_load_lds(
        (const __attribute__((address_space(1))) void*)g,
        (__attribute__((address_space(3))) void*)l, 16, 0, 0);
}

// ---------------------------------------------------------------------------
// GEMM: C[M][N] = A[M][K] * W[N][K]^T   (A row-major, W row-major = B^T input)
// MODE 0: A = hidden fp32; W in {wq,wk,wv} by blockIdx.y/16;
//         C bf16 -> Q/K row-major [bh][s][d], V transposed [bh][d][s]
// MODE 1: A = attn-out bf16; W = wo fp32; C fp32 [M][N]
// ---------------------------------------------------------------------------
template<int MODE>
__global__ __launch_bounds__(256, 2)
void gemm_bt(const float* Af, const short* Ab,
             const float* W0, const float* W1, const float* W2,
             short* Oq, short* Ok, short* Ov, float* Of)
{
    __shared__ short smem[2 * 128 * 64];
    short* As = smem;
    short* Bs = smem + 128 * 64;

    const int tid  = threadIdx.x;
    const int lane = tid & 63;
    const int wv   = tid >> 6;
    const int wr   = wv >> 1, wc = wv & 1;
    const int fr   = lane & 15, fg = lane >> 4;

    const int mt = blockIdx.x;
    int nt = blockIdx.y;
    const float* W = W0;
    short* Ob = Oq;
    int osel = 0;
    if (MODE == 0) {
        osel = nt >> 4; nt &= 15;
        W  = (osel == 0) ? W0 : (osel == 1) ? W1 : W2;
        Ob = (osel == 0) ? Oq : (osel == 1) ? Ok : Ov;
    }
    const int row0 = mt * 128, col0 = nt * 128;

    f32x4 acc[4][4];
#pragma unroll
    for (int m = 0; m < 4; ++m)
#pragma unroll
        for (int n = 0; n < 4; ++n) acc[m][n] = (f32x4){0.f, 0.f, 0.f, 0.f};

    for (int k0 = 0; k0 < HIDDEN; k0 += 64) {
        __syncthreads();  // previous iter's LDS reads done before restage
        // ---- stage A (128x64 bf16, XOR-swizzled 16B blocks) ----
#pragma unroll
        for (int it = 0; it < 4; ++it) {
            int c = it * 256 + tid;
            int r = c >> 3, blk = c & 7;
            short v[8];
            if (MODE == 0) {
                const float* src = Af + (size_t)(row0 + r) * HIDDEN + k0 + blk * 8;
                f32x4 lo = *(const f32x4*)src;
                f32x4 hi = *(const f32x4*)(src + 4);
#pragma unroll
                for (int j = 0; j < 4; ++j) { v[j] = f2bf(lo[j]); v[4 + j] = f2bf(hi[j]); }
            } else {
                const short* src = Ab + (size_t)(row0 + r) * HIDDEN + k0 + blk * 8;
                *(bf16x8*)v = *(const bf16x8*)src;
            }
            *(bf16x8*)&As[r * 64 + ((blk ^ (r & 7)) * 8)] = *(bf16x8*)v;
        }
        // ---- stage B (fp32 weights -> bf16) ----
#pragma unroll
        for (int it = 0; it < 4; ++it) {
            int c = it * 256 + tid;
            int r = c >> 3, blk = c & 7;
            const float* src = W + (size_t)(col0 + r) * HIDDEN + k0 + blk * 8;
            f32x4 lo = *(const f32x4*)src;
            f32x4 hi = *(const f32x4*)(src + 4);
            short v[8];
#pragma unroll
            for (int j = 0; j < 4; ++j) { v[j] = f2bf(lo[j]); v[4 + j] = f2bf(hi[j]); }
            *(bf16x8*)&Bs[r * 64 + ((blk ^ (r & 7)) * 8)] = *(bf16x8*)v;
        }
        __syncthreads();
        // ---- MFMA: 2 K-steps of 32 ----
#pragma unroll
        for (int ks = 0; ks < 2; ++ks) {
            bf16x8 a[4], b[4];
#pragma unroll
            for (int m = 0; m < 4; ++m) {
                int r = wr * 64 + m * 16 + fr;
                a[m] = *(const bf16x8*)&As[r * 64 + (((ks * 4 + fg) ^ (r & 7)) * 8)];
            }
#pragma unroll
            for (int n = 0; n < 4; ++n) {
                int r = wc * 64 + n * 16 + fr;
                b[n] = *(const bf16x8*)&Bs[r * 64 + (((ks * 4 + fg) ^ (r & 7)) * 8)];
            }
#pragma unroll
            for (int m = 0; m < 4; ++m)
#pragma unroll
                for (int n = 0; n < 4; ++n)
                    acc[m][n] = mfma16(a[m], b[n], acc[m][n]);
        }
    }

    // ---- epilogue ----
    if (MODE == 0 && osel == 2) {
        // V: transpose through LDS, store [bh][d][s] coalesced
        __syncthreads();
#pragma unroll
        for (int m = 0; m < 4; ++m)
#pragma unroll
            for (int j = 0; j < 4; ++j) {
                int row = wr * 64 + m * 16 + fg * 4 + j;   // s within tile
#pragma unroll
                for (int n = 0; n < 4; ++n) {
                    int col = wc * 64 + n * 16 + fr;       // d within tile
                    smem[col * 128 + (((row >> 3) ^ (col & 15)) * 8) + (row & 7)] =
                        f2bf(acc[m][n][j]);
                }
            }
        __syncthreads();
        const int b_ = row0 >> 11;                  // batch (tile never crosses)
        const int bh = b_ * NH + nt;                // h == nt for V
        const int s0 = row0 & (S_LEN - 1);
#pragma unroll
        for (int it = 0; it < 8; ++it) {
            int c = it * 256 + tid;                 // 0..2047
            int d = c >> 4, sb = c & 15;
            bf16x8 vv = *(const bf16x8*)&smem[d * 128 + ((sb ^ (d & 15)) * 8)];
            *(bf16x8*)(Ov + ((size_t)bh * HD + d) * S_LEN + s0 + sb * 8) = vv;
        }
    } else {
#pragma unroll
        for (int m = 0; m < 4; ++m)
#pragma unroll
            for (int j = 0; j < 4; ++j) {
                int mrow = row0 + wr * 64 + m * 16 + fg * 4 + j;
#pragma unroll
                for (int n = 0; n < 4; ++n) {
                    int col = col0 + wc * 64 + n * 16 + fr;
                    float val = acc[m][n][j];
                    if (MODE == 0) {
                        int b_ = mrow >> 11, s = mrow & (S_LEN - 1);
                        int h = col >> 7, d = col & (HD - 1);
                        Ob[((size_t)(b_ * NH + h) * S_LEN + s) * HD + d] = f2bf(val);
                    } else {
                        Of[(size_t)mrow * HIDDEN + col] = val;
                    }
                }
            }
    }
}

// ---------------------------------------------------------------------------
// RoPE table: [S][64] pairs (cos, sin)
// ---------------------------------------------------------------------------
__global__ void rope_table_k(float* tab)
{
    int i = blockIdx.x * 256 + threadIdx.x;
    if (i >= S_LEN * 64) return;
    int s = i >> 6, d = i & 63;
    float inv = 1.0f / powf(10000.0f, (float)d * (1.0f / 64.0f));
    float ang = (float)s * inv;
    tab[2 * i]     = cosf(ang);
    tab[2 * i + 1] = sinf(ang);
}

// RoPE apply to Q (with 1/sqrt(Hd) folded in) and K, in-place, bf16.
__global__ void rope_apply_k(short* Q, short* K, const float* tab)
{
    int i = blockIdx.x * 256 + threadIdx.x;   // BATCH*NH*S_LEN*64
    if (i >= BATCH * NH * S_LEN * 64) return;
    int d  = i & 63;
    int s  = (i >> 6) & (S_LEN - 1);
    int bh = i >> 17;
    float c  = tab[2 * (s * 64 + d)];
    float sn = tab[2 * (s * 64 + d) + 1];
    size_t base = ((size_t)bh * S_LEN + s) * HD + d;
    const float qs = 0.08838834764831845f;    // 1/sqrt(128)
    float q1 = bf2f(Q[base]), q2 = bf2f(Q[base + 64]);
    Q[base]      = f2bf((q1 * c - q2 * sn) * qs);
    Q[base + 64] = f2bf((q2 * c + q1 * sn) * qs);
    float k1 = bf2f(K[base]), k2 = bf2f(K[base + 64]);
    K[base]      = f2bf(k1 * c - k2 * sn);
    K[base + 64] = f2bf(k2 * c + k1 * sn);
}

// ---------------------------------------------------------------------------
// Causal flash attention. Grid: (16 q-tiles, 32 bh). 4 waves x 32 q-rows.
// K [bh][s][d] row-major; V [bh][d][s] transposed. KV tile = 32.
// ---------------------------------------------------------------------------
__global__ __launch_bounds__(256, 2)
void attn_k(const short* Q, const short* K, const short* Vt, short* AO)
{
    __shared__ short Ks[32 * 128];     // swizzled: 16B blocks ^ (krow&15)
    __shared__ short Vs[128 * 32];     // swizzled: 16B blocks ^ (d&3)
    __shared__ short Ps[4][32 * 32];   // per-wave P, swizzled ^(q&3)

    const int tid = threadIdx.x, lane = tid & 63, wv = tid >> 6;
    const int fr = lane & 15, fg = lane >> 4;
    const int qt = blockIdx.x, bh = blockIdx.y;

    const short* Qb = Q  + (size_t)bh * S_LEN * HD;
    const short* Kb = K  + (size_t)bh * S_LEN * HD;
    const short* Vb = Vt + (size_t)bh * HD * S_LEN;
    const int qbase = qt * 128 + wv * 32;

    // Q fragments in registers: [mi][ks], row = qbase+mi*16+fr, k = ks*32+fg*8
    bf16x8 qf[2][4];
#pragma unroll
    for (int mi = 0; mi < 2; ++mi)
#pragma unroll
        for (int ks = 0; ks < 4; ++ks)
            qf[mi][ks] = *(const bf16x8*)(Qb + (size_t)(qbase + mi * 16 + fr) * HD
                                          + ks * 32 + fg * 8);

    f32x4 o[2][8];
    float mrun[2][4], lrun[2][4];
#pragma unroll
    for (int mi = 0; mi < 2; ++mi) {
#pragma unroll
        for (int nd = 0; nd < 8; ++nd) o[mi][nd] = (f32x4){0.f, 0.f, 0.f, 0.f};
#pragma unroll
        for (int j = 0; j < 4; ++j) { mrun[mi][j] = -1e30f; lrun[mi][j] = 0.f; }
    }

    const int ntiles = (qt + 1) * 4;
    for (int t = 0; t < ntiles; ++t) {
        const int kb = t * 32;
        __syncthreads();
        // stage K tile 32x128 (pre-swizzled global source, linear LDS dest)
#pragma unroll
        for (int i = 0; i < 2; ++i) {
            int c = i * 256 + tid;
            int r = c >> 4, blk = c & 15;
            gload16(Kb + (size_t)(kb + r) * HD + ((blk ^ (r & 15)) * 8),
                    (char*)Ks + (i * 256 + wv * 64) * 16);
        }
        // stage V tile 128x32 from transposed V
#pragma unroll
        for (int i = 0; i < 2; ++i) {
            int c = i * 256 + tid;
            int r = c >> 2, blk = c & 3;          // r = d row
            gload16(Vb + (size_t)r * S_LEN + kb + ((blk ^ (r & 3)) * 8),
                    (char*)Vs + (i * 256 + wv * 64) * 16);
        }
        __syncthreads();

        if (kb <= qbase + 31) {                    // wave-uniform causal skip
            // ---- QK^T ----
            f32x4 sc[2][2];
#pragma unroll
            for (int mi = 0; mi < 2; ++mi)
#pragma unroll
                for (int ni = 0; ni < 2; ++ni) sc[mi][ni] = (f32x4){0.f, 0.f, 0.f, 0.f};
#pragma unroll
            for (int ks = 0; ks < 4; ++ks) {
                bf16x8 kf[2];
#pragma unroll
                for (int ni = 0; ni < 2; ++ni) {
                    int kc = ni * 16 + fr;
                    kf[ni] = *(const bf16x8*)&Ks[kc * 128 + (((ks * 4 + fg) ^ (kc & 15)) * 8)];
                }
#pragma unroll
                for (int mi = 0; mi < 2; ++mi)
#pragma unroll
                    for (int ni = 0; ni < 2; ++ni)
                        sc[mi][ni] = mfma16(qf[mi][ks], kf[ni], sc[mi][ni]);
            }
            // ---- mask + online softmax ----
#pragma unroll
            for (int mi = 0; mi < 2; ++mi) {
#pragma unroll
                for (int j = 0; j < 4; ++j) {
                    int qrow = qbase + mi * 16 + fg * 4 + j;
#pragma unroll
                    for (int ni = 0; ni < 2; ++ni) {
                        int kcol = kb + ni * 16 + fr;
                        if (kcol > qrow) sc[mi][ni][j] = -1e30f;
                    }
                    float mx = fmaxf(sc[mi][0][j], sc[mi][1][j]);
                    mx = fmaxf(mx, __shfl_xor(mx, 1));
                    mx = fmaxf(mx, __shfl_xor(mx, 2));
                    mx = fmaxf(mx, __shfl_xor(mx, 4));
                    mx = fmaxf(mx, __shfl_xor(mx, 8));
                    float mnew  = fmaxf(mrun[mi][j], mx);
                    float scale = __expf(mrun[mi][j] - mnew);
                    mrun[mi][j] = mnew;
                    float rs = 0.f;
#pragma unroll
                    for (int ni = 0; ni < 2; ++ni) {
                        float p = __expf(sc[mi][ni][j] - mnew);
                        sc[mi][ni][j] = p;
                        rs += p;
                    }
                    rs += __shfl_xor(rs, 1);
                    rs += __shfl_xor(rs, 2);
                    rs += __shfl_xor(rs, 4);
                    rs += __shfl_xor(rs, 8);
                    lrun[mi][j] = lrun[mi][j] * scale + rs;
#pragma unroll
                    for (int nd = 0; nd < 8; ++nd) o[mi][nd][j] *= scale;
                    // write P (bf16) to per-wave LDS, swizzled
#pragma unroll
                    for (int ni = 0; ni < 2; ++ni) {
                        int ql = mi * 16 + fg * 4 + j;
                        int kl = ni * 16 + fr;
                        Ps[wv][ql * 32 + (((kl >> 3) ^ (ql & 3)) * 8) + (kl & 7)] =
                            f2bf(sc[mi][ni][j]);
                    }
                }
            }
            asm volatile("s_waitcnt lgkmcnt(0)" ::: "memory");
            // ---- P @ V ----
            bf16x8 pa[2];
#pragma unroll
            for (int mi = 0; mi < 2; ++mi) {
                int ql = mi * 16 + fr;
                pa[mi] = *(const bf16x8*)&Ps[wv][ql * 32 + ((fg ^ (ql & 3)) * 8)];
            }
#pragma unroll
            for (int nd = 0; nd < 8; ++nd) {
                int d = nd * 16 + fr;
                bf16x8 vf = *(const bf16x8*)&Vs[d * 32 + ((fg ^ (d & 3)) * 8)];
#pragma unroll
                for (int mi = 0; mi < 2; ++mi)
                    o[mi][nd] = mfma16(pa[mi], vf, o[mi][nd]);
            }
        }
    }

    // ---- epilogue: normalize, write [b][s][h*128+d] bf16 ----
    const int b_ = bh >> 4, h = bh & 15;
#pragma unroll
    for (int mi = 0; mi < 2; ++mi)
#pragma unroll
        for (int j = 0; j < 4; ++j) {
            float inv = 1.0f / lrun[mi][j];
            int srow = qbase + mi * 16 + fg * 4 + j;
#pragma unroll
            for (int nd = 0; nd < 8; ++nd) {
                int col = h * HD + nd * 16 + fr;
                AO[((size_t)b_ * S_LEN + srow) * HIDDEN + col] =
                    f2bf(o[mi][nd][j] * inv);
            }
        }
}

// ---------------------------------------------------------------------------
extern "C" void kernel_launch(void* const* d_in, const int* in_sizes, int n_in,
                              void* d_out, int out_size, void* d_ws, size_t ws_size,
                              hipStream_t stream)
{
    const float* hs = (const float*)d_in[0];
    const float* wq = (const float*)d_in[1];
    const float* wk = (const float*)d_in[2];
    const float* wvp = (const float*)d_in[3];
    const float* wo = (const float*)d_in[4];
    float* out = (float*)d_out;

    char* ws = (char*)d_ws;
    const size_t SZ = (size_t)MROWS * HIDDEN * 2;   // 16 MiB per bf16 tensor
    short* Qb  = (short*)(ws);
    short* Kb  = (short*)(ws + SZ);
    short* Vb  = (short*)(ws + 2 * SZ);              // [bh][d][s]
    short* AO  = (short*)(ws + 3 * SZ);
    float* tab = (float*)(ws + 4 * SZ);              // 1 MiB

    rope_table_k<<<dim3(512), dim3(256), 0, stream>>>(tab);
    gemm_bt<0><<<dim3(32, 48), dim3(256), 0, stream>>>(
        hs, nullptr, wq, wk, wvp, Qb, Kb, Vb, nullptr);
    rope_apply_k<<<dim3(16384), dim3(256), 0, stream>>>(Qb, Kb, tab);
    attn_k<<<dim3(16, 32), dim3(256), 0, stream>>>(Qb, Kb, Vb, AO);
    gemm_bt<1><<<dim3(32, 16), dim3(256), 0, stream>>>(
        nullptr, AO, wo, nullptr, nullptr, nullptr, nullptr, nullptr, out);
}

// Round 2
// 473.821 us; speedup vs baseline: 1.5130x; 1.5130x over previous
//
#include <hip/hip_runtime.h>
#include <hip/hip_bf16.h>

#define S_LEN  2048
#define BATCH  2
#define NH     16
#define HD     128
#define HIDDEN 2048
#define MROWS  (BATCH*S_LEN)   // 4096

typedef __attribute__((ext_vector_type(8))) short bf16x8;
typedef __attribute__((ext_vector_type(4))) float f32x4;

__device__ __forceinline__ float bf2f(short s) {
    union { float f; unsigned int u; } v;
    v.u = ((unsigned int)(unsigned short)s) << 16;
    return v.f;
}
__device__ __forceinline__ short f2bf(float f) {
    union { float f; unsigned int u; } v;
    v.f = f;
    unsigned int r = v.u + 0x7fffu + ((v.u >> 16) & 1u);   // RNE, inputs never NaN
    return (short)(r >> 16);
}
__device__ __forceinline__ f32x4 mfma16(bf16x8 a, bf16x8 b, f32x4 c) {
    return __builtin_amdgcn_mfma_f32_16x16x32_bf16(a, b, c, 0, 0, 0);
}
__device__ __forceinline__ void gload16(const void* g, void* l) {
    __builtin_amdgcn_global_load_lds(
        (const __attribute__((address_space(1))) void*)g,
        (__attribute__((address_space(3))) void*)l, 16, 0, 0);
}

// ---------------------------------------------------------------------------
// Cast fp32 -> bf16: hidden (2 x 4M segs), wq, wk, wv, wo (1 seg each).
// dst layout: [hidden | wq | wk | wv | wo] flat.
// ---------------------------------------------------------------------------
#define SEG (4194304)
__global__ void cast_k(const float* hs, const float* wq, const float* wk,
                       const float* wv, const float* wo, short* dst)
{
    size_t i = ((size_t)blockIdx.x * 256 + threadIdx.x) * 8;  // element index
    int seg = (int)(i >> 22);
    const float* s;
    size_t off;
    if (seg < 2)      { s = hs; off = i; }
    else if (seg == 2){ s = wq; off = i - 2 * (size_t)SEG; }
    else if (seg == 3){ s = wk; off = i - 3 * (size_t)SEG; }
    else if (seg == 4){ s = wv; off = i - 4 * (size_t)SEG; }
    else              { s = wo; off = i - 5 * (size_t)SEG; }
    f32x4 lo = *(const f32x4*)(s + off);
    f32x4 hi = *(const f32x4*)(s + off + 4);
    short v[8];
#pragma unroll
    for (int j = 0; j < 4; ++j) { v[j] = f2bf(lo[j]); v[4 + j] = f2bf(hi[j]); }
    *(bf16x8*)(dst + i) = *(bf16x8*)v;
}

// ---------------------------------------------------------------------------
// GEMM: C[M][N] = A[M][K] * W[N][K]^T, all bf16 operands (m97 structure:
// global_load_lds width-16 staging, pre-swizzled global source, swizzled
// ds_read_b128, 128x128 tile, BK=64, 4 waves each 64x64).
// MODE 0: W in {wq,wk,wv} by blockIdx.y/16; C bf16 -> Q/K [bh][s][d],
//         V transposed [bh][d][s]
// MODE 1: W = wo; C fp32 [M][N]
// ---------------------------------------------------------------------------
template<int MODE>
__global__ __launch_bounds__(256, 2)
void gemm_bt(const short* A, const short* W0, const short* W1, const short* W2,
             short* Oq, short* Ok, short* Ov, float* Of)
{
    __shared__ short smem[2 * 128 * 64];
    short* As = smem;
    short* Bs = smem + 128 * 64;

    const int tid  = threadIdx.x;
    const int lane = tid & 63;
    const int wv   = tid >> 6;
    const int wr   = wv >> 1, wc = wv & 1;
    const int fr   = lane & 15, fg = lane >> 4;

    const int mt = blockIdx.x;
    int nt = blockIdx.y;
    const short* W = W0;
    short* Ob = Oq;
    int osel = 0;
    if (MODE == 0) {
        osel = nt >> 4; nt &= 15;
        W  = (osel == 0) ? W0 : (osel == 1) ? W1 : W2;
        Ob = (osel == 0) ? Oq : (osel == 1) ? Ok : Ov;
    }
    const int row0 = mt * 128, col0 = nt * 128;

    // staging coords: c = it*256+tid; row r=c>>3, dest block slot b=c&7;
    // source block = b ^ (r&7)  (XOR involution, read side applies same XOR)
    const int sr = tid >> 3, sb = tid & 7;

    f32x4 acc[4][4];
#pragma unroll
    for (int m = 0; m < 4; ++m)
#pragma unroll
        for (int n = 0; n < 4; ++n) acc[m][n] = (f32x4){0.f, 0.f, 0.f, 0.f};

    for (int k0 = 0; k0 < HIDDEN; k0 += 64) {
        __syncthreads();  // prev iter's LDS reads done before restage
#pragma unroll
        for (int it = 0; it < 4; ++it) {
            int r = it * 32 + sr;
            gload16(A + (size_t)(row0 + r) * HIDDEN + k0 + ((sb ^ (r & 7)) * 8),
                    (char*)As + (it * 256 + wv * 64) * 16);
        }
#pragma unroll
        for (int it = 0; it < 4; ++it) {
            int r = it * 32 + sr;
            gload16(W + (size_t)(col0 + r) * HIDDEN + k0 + ((sb ^ (r & 7)) * 8),
                    (char*)Bs + (it * 256 + wv * 64) * 16);
        }
        __syncthreads();  // compiler drains vmcnt before barrier
#pragma unroll
        for (int ks = 0; ks < 2; ++ks) {
            bf16x8 a[4], b[4];
#pragma unroll
            for (int m = 0; m < 4; ++m) {
                int r = wr * 64 + m * 16 + fr;
                a[m] = *(const bf16x8*)&As[r * 64 + (((ks * 4 + fg) ^ (r & 7)) * 8)];
            }
#pragma unroll
            for (int n = 0; n < 4; ++n) {
                int r = wc * 64 + n * 16 + fr;
                b[n] = *(const bf16x8*)&Bs[r * 64 + (((ks * 4 + fg) ^ (r & 7)) * 8)];
            }
#pragma unroll
            for (int m = 0; m < 4; ++m)
#pragma unroll
                for (int n = 0; n < 4; ++n)
                    acc[m][n] = mfma16(a[m], b[n], acc[m][n]);
        }
    }

    // ---- epilogue ----
    if (MODE == 0 && osel == 2) {
        // V: transpose through LDS, store [bh][d][s] coalesced
        __syncthreads();
#pragma unroll
        for (int m = 0; m < 4; ++m)
#pragma unroll
            for (int j = 0; j < 4; ++j) {
                int row = wr * 64 + m * 16 + fg * 4 + j;   // s within tile
#pragma unroll
                for (int n = 0; n < 4; ++n) {
                    int col = wc * 64 + n * 16 + fr;       // d within tile
                    smem[col * 128 + (((row >> 3) ^ (col & 15)) * 8) + (row & 7)] =
                        f2bf(acc[m][n][j]);
                }
            }
        __syncthreads();
        const int b_ = row0 >> 11;                  // batch (tile never crosses)
        const int bh = b_ * NH + nt;                // h == nt for V
        const int s0 = row0 & (S_LEN - 1);
#pragma unroll
        for (int it = 0; it < 8; ++it) {
            int c = it * 256 + tid;                 // 0..2047
            int d = c >> 4, sbk = c & 15;
            bf16x8 vv = *(const bf16x8*)&smem[d * 128 + ((sbk ^ (d & 15)) * 8)];
            *(bf16x8*)(Ov + ((size_t)bh * HD + d) * S_LEN + s0 + sbk * 8) = vv;
        }
    } else {
#pragma unroll
        for (int m = 0; m < 4; ++m)
#pragma unroll
            for (int j = 0; j < 4; ++j) {
                int mrow = row0 + wr * 64 + m * 16 + fg * 4 + j;
#pragma unroll
                for (int n = 0; n < 4; ++n) {
                    int col = col0 + wc * 64 + n * 16 + fr;
                    float val = acc[m][n][j];
                    if (MODE == 0) {
                        int b_ = mrow >> 11, s = mrow & (S_LEN - 1);
                        int h = col >> 7, d = col & (HD - 1);
                        Ob[((size_t)(b_ * NH + h) * S_LEN + s) * HD + d] = f2bf(val);
                    } else {
                        Of[(size_t)mrow * HIDDEN + col] = val;
                    }
                }
            }
    }
}

// ---------------------------------------------------------------------------
// RoPE table: [S][64] pairs (cos, sin)
// ---------------------------------------------------------------------------
__global__ void rope_table_k(float* tab)
{
    int i = blockIdx.x * 256 + threadIdx.x;
    if (i >= S_LEN * 64) return;
    int s = i >> 6, d = i & 63;
    float inv = 1.0f / powf(10000.0f, (float)d * (1.0f / 64.0f));
    float ang = (float)s * inv;
    tab[2 * i]     = cosf(ang);
    tab[2 * i + 1] = sinf(ang);
}

// RoPE apply to Q (with 1/sqrt(Hd) folded in) and K, in-place, vectorized.
// thread = (bh, s, d-group of 8). total = 32*2048*8 = 524288 threads.
__global__ void rope_apply_k(short* Q, short* K, const float* tab)
{
    int i = blockIdx.x * 256 + threadIdx.x;
    int d8 = i & 7;
    int s  = (i >> 3) & (S_LEN - 1);
    int bh = i >> 14;
    size_t base = ((size_t)bh * S_LEN + s) * HD + d8 * 8;
    const float* tp = tab + (s * 64 + d8 * 8) * 2;
    f32x4 t[4];
#pragma unroll
    for (int j = 0; j < 4; ++j) t[j] = *(const f32x4*)(tp + j * 4);

    bf16x8 q1 = *(bf16x8*)(Q + base), q2 = *(bf16x8*)(Q + base + 64);
    bf16x8 k1 = *(bf16x8*)(K + base), k2 = *(bf16x8*)(K + base + 64);
    short oq1[8], oq2[8], ok1[8], ok2[8];
    const float qs = 0.08838834764831845f;    // 1/sqrt(128)
#pragma unroll
    for (int j = 0; j < 8; ++j) {
        float c  = t[j >> 1][(j & 1) * 2];
        float sn = t[j >> 1][(j & 1) * 2 + 1];
        float a1 = bf2f(q1[j]), a2 = bf2f(q2[j]);
        oq1[j] = f2bf((a1 * c - a2 * sn) * qs);
        oq2[j] = f2bf((a2 * c + a1 * sn) * qs);
        float b1 = bf2f(k1[j]), b2 = bf2f(k2[j]);
        ok1[j] = f2bf(b1 * c - b2 * sn);
        ok2[j] = f2bf(b2 * c + b1 * sn);
    }
    *(bf16x8*)(Q + base)      = *(bf16x8*)oq1;
    *(bf16x8*)(Q + base + 64) = *(bf16x8*)oq2;
    *(bf16x8*)(K + base)      = *(bf16x8*)ok1;
    *(bf16x8*)(K + base + 64) = *(bf16x8*)ok2;
}

// ---------------------------------------------------------------------------
// Causal flash attention. Grid: (16 q-tiles, 32 bh). 4 waves x 32 q-rows.
// K [bh][s][d] row-major; V [bh][d][s] transposed. KV tile = 32.
// ---------------------------------------------------------------------------
__global__ __launch_bounds__(256, 2)
void attn_k(const short* Q, const short* K, const short* Vt, short* AO)
{
    __shared__ short Ks[32 * 128];     // swizzled: 16B blocks ^ (krow&15)
    __shared__ short Vs[128 * 32];     // swizzled: 16B blocks ^ (d&3)
    __shared__ short Ps[4][32 * 32];   // per-wave P, swizzled ^(q&3)

    const int tid = threadIdx.x, lane = tid & 63, wv = tid >> 6;
    const int fr = lane & 15, fg = lane >> 4;
    const int qt = blockIdx.x, bh = blockIdx.y;

    const short* Qb = Q  + (size_t)bh * S_LEN * HD;
    const short* Kb = K  + (size_t)bh * S_LEN * HD;
    const short* Vb = Vt + (size_t)bh * HD * S_LEN;
    const int qbase = qt * 128 + wv * 32;

    bf16x8 qf[2][4];
#pragma unroll
    for (int mi = 0; mi < 2; ++mi)
#pragma unroll
        for (int ks = 0; ks < 4; ++ks)
            qf[mi][ks] = *(const bf16x8*)(Qb + (size_t)(qbase + mi * 16 + fr) * HD
                                          + ks * 32 + fg * 8);

    f32x4 o[2][8];
    float mrun[2][4], lrun[2][4];
#pragma unroll
    for (int mi = 0; mi < 2; ++mi) {
#pragma unroll
        for (int nd = 0; nd < 8; ++nd) o[mi][nd] = (f32x4){0.f, 0.f, 0.f, 0.f};
#pragma unroll
        for (int j = 0; j < 4; ++j) { mrun[mi][j] = -1e30f; lrun[mi][j] = 0.f; }
    }

    const int ntiles = (qt + 1) * 4;
    for (int t = 0; t < ntiles; ++t) {
        const int kb = t * 32;
        __syncthreads();
#pragma unroll
        for (int i = 0; i < 2; ++i) {
            int c = i * 256 + tid;
            int r = c >> 4, blk = c & 15;
            gload16(Kb + (size_t)(kb + r) * HD + ((blk ^ (r & 15)) * 8),
                    (char*)Ks + (i * 256 + wv * 64) * 16);
        }
#pragma unroll
        for (int i = 0; i < 2; ++i) {
            int c = i * 256 + tid;
            int r = c >> 2, blk = c & 3;          // r = d row
            gload16(Vb + (size_t)r * S_LEN + kb + ((blk ^ (r & 3)) * 8),
                    (char*)Vs + (i * 256 + wv * 64) * 16);
        }
        __syncthreads();

        if (kb <= qbase + 31) {                    // wave-uniform causal skip
            f32x4 sc[2][2];
#pragma unroll
            for (int mi = 0; mi < 2; ++mi)
#pragma unroll
                for (int ni = 0; ni < 2; ++ni) sc[mi][ni] = (f32x4){0.f, 0.f, 0.f, 0.f};
#pragma unroll
            for (int ks = 0; ks < 4; ++ks) {
                bf16x8 kf[2];
#pragma unroll
                for (int ni = 0; ni < 2; ++ni) {
                    int kc = ni * 16 + fr;
                    kf[ni] = *(const bf16x8*)&Ks[kc * 128 + (((ks * 4 + fg) ^ (kc & 15)) * 8)];
                }
#pragma unroll
                for (int mi = 0; mi < 2; ++mi)
#pragma unroll
                    for (int ni = 0; ni < 2; ++ni)
                        sc[mi][ni] = mfma16(qf[mi][ks], kf[ni], sc[mi][ni]);
            }
#pragma unroll
            for (int mi = 0; mi < 2; ++mi) {
#pragma unroll
                for (int j = 0; j < 4; ++j) {
                    int qrow = qbase + mi * 16 + fg * 4 + j;
#pragma unroll
                    for (int ni = 0; ni < 2; ++ni) {
                        int kcol = kb + ni * 16 + fr;
                        if (kcol > qrow) sc[mi][ni][j] = -1e30f;
                    }
                    float mx = fmaxf(sc[mi][0][j], sc[mi][1][j]);
                    mx = fmaxf(mx, __shfl_xor(mx, 1));
                    mx = fmaxf(mx, __shfl_xor(mx, 2));
                    mx = fmaxf(mx, __shfl_xor(mx, 4));
                    mx = fmaxf(mx, __shfl_xor(mx, 8));
                    float mnew  = fmaxf(mrun[mi][j], mx);
                    float scale = __expf(mrun[mi][j] - mnew);
                    mrun[mi][j] = mnew;
                    float rs = 0.f;
#pragma unroll
                    for (int ni = 0; ni < 2; ++ni) {
                        float p = __expf(sc[mi][ni][j] - mnew);
                        sc[mi][ni][j] = p;
                        rs += p;
                    }
                    rs += __shfl_xor(rs, 1);
                    rs += __shfl_xor(rs, 2);
                    rs += __shfl_xor(rs, 4);
                    rs += __shfl_xor(rs, 8);
                    lrun[mi][j] = lrun[mi][j] * scale + rs;
#pragma unroll
                    for (int nd = 0; nd < 8; ++nd) o[mi][nd][j] *= scale;
#pragma unroll
                    for (int ni = 0; ni < 2; ++ni) {
                        int ql = mi * 16 + fg * 4 + j;
                        int kl = ni * 16 + fr;
                        Ps[wv][ql * 32 + (((kl >> 3) ^ (ql & 3)) * 8) + (kl & 7)] =
                            f2bf(sc[mi][ni][j]);
                    }
                }
            }
            asm volatile("s_waitcnt lgkmcnt(0)" ::: "memory");
            bf16x8 pa[2];
#pragma unroll
            for (int mi = 0; mi < 2; ++mi) {
                int ql = mi * 16 + fr;
                pa[mi] = *(const bf16x8*)&Ps[wv][ql * 32 + ((fg ^ (ql & 3)) * 8)];
            }
#pragma unroll
            for (int nd = 0; nd < 8; ++nd) {
                int d = nd * 16 + fr;
                bf16x8 vf = *(const bf16x8*)&Vs[d * 32 + ((fg ^ (d & 3)) * 8)];
#pragma unroll
                for (int mi = 0; mi < 2; ++mi)
                    o[mi][nd] = mfma16(pa[mi], vf, o[mi][nd]);
            }
        }
    }

    const int b_ = bh >> 4, h = bh & 15;
#pragma unroll
    for (int mi = 0; mi < 2; ++mi)
#pragma unroll
        for (int j = 0; j < 4; ++j) {
            float inv = 1.0f / lrun[mi][j];
            int srow = qbase + mi * 16 + fg * 4 + j;
#pragma unroll
            for (int nd = 0; nd < 8; ++nd) {
                int col = h * HD + nd * 16 + fr;
                AO[((size_t)b_ * S_LEN + srow) * HIDDEN + col] =
                    f2bf(o[mi][nd][j] * inv);
            }
        }
}

// ---------------------------------------------------------------------------
extern "C" void kernel_launch(void* const* d_in, const int* in_sizes, int n_in,
                              void* d_out, int out_size, void* d_ws, size_t ws_size,
                              hipStream_t stream)
{
    const float* hs = (const float*)d_in[0];
    const float* wq = (const float*)d_in[1];
    const float* wk = (const float*)d_in[2];
    const float* wvp = (const float*)d_in[3];
    const float* wo = (const float*)d_in[4];
    float* out = (float*)d_out;

    char* ws = (char*)d_ws;
    // bf16 cast region: [hidden(8.4M) | wq | wk | wv | wo] shorts
    short* CB  = (short*)ws;
    short* Hb  = CB;
    short* Wqb = CB + 2 * (size_t)SEG;
    short* Wkb = CB + 3 * (size_t)SEG;
    short* Wvb = CB + 4 * (size_t)SEG;
    short* Wob = CB + 5 * (size_t)SEG;
    short* Qb  = (short*)(ws + 50331648);
    short* Kb  = (short*)(ws + 67108864);
    short* Vb  = (short*)(ws + 83886080);   // [bh][d][s]
    short* AO  = Hb;                         // alias: hidden dead after gemm<0>
    float* tab = (float*)(ws + 100663296);

    cast_k<<<dim3(12288), dim3(256), 0, stream>>>(hs, wq, wk, wvp, wo, CB);
    rope_table_k<<<dim3(512), dim3(256), 0, stream>>>(tab);
    gemm_bt<0><<<dim3(32, 48), dim3(256), 0, stream>>>(
        Hb, Wqb, Wkb, Wvb, Qb, Kb, Vb, nullptr);
    rope_apply_k<<<dim3(2048), dim3(256), 0, stream>>>(Qb, Kb, tab);
    attn_k<<<dim3(16, 32), dim3(256), 0, stream>>>(Qb, Kb, Vb, AO);
    gemm_bt<1><<<dim3(32, 16), dim3(256), 0, stream>>>(
        AO, Wob, nullptr, nullptr, nullptr, nullptr, nullptr, out);
}

// Round 3
// 471.411 us; speedup vs baseline: 1.5207x; 1.0051x over previous
//
#include <hip/hip_runtime.h>
#include <hip/hip_bf16.h>

#define S_LEN  2048
#define BATCH  2
#define NH     16
#define HD     128
#define HIDDEN 2048
#define MROWS  (BATCH*S_LEN)   // 4096

typedef __attribute__((ext_vector_type(8))) short bf16x8;
typedef __attribute__((ext_vector_type(4))) float f32x4;

__device__ __forceinline__ float bf2f(short s) {
    union { float f; unsigned int u; } v;
    v.u = ((unsigned int)(unsigned short)s) << 16;
    return v.f;
}
__device__ __forceinline__ short f2bf(float f) {
    union { float f; unsigned int u; } v;
    v.f = f;
    unsigned int r = v.u + 0x7fffu + ((v.u >> 16) & 1u);   // RNE, inputs never NaN
    return (short)(r >> 16);
}
__device__ __forceinline__ f32x4 mfma16(bf16x8 a, bf16x8 b, f32x4 c) {
    return __builtin_amdgcn_mfma_f32_16x16x32_bf16(a, b, c, 0, 0, 0);
}
__device__ __forceinline__ void gload16(const void* g, void* l) {
    __builtin_amdgcn_global_load_lds(
        (const __attribute__((address_space(1))) void*)g,
        (__attribute__((address_space(3))) void*)l, 16, 0, 0);
}

// ---------------------------------------------------------------------------
// Cast fp32 -> bf16: hidden (2 x 4M segs), wq, wk, wv, wo (1 seg each).
// ---------------------------------------------------------------------------
#define SEG (4194304)
__global__ void cast_k(const float* hs, const float* wq, const float* wk,
                       const float* wv, const float* wo, short* dst)
{
    size_t i = ((size_t)blockIdx.x * 256 + threadIdx.x) * 8;
    int seg = (int)(i >> 22);
    const float* s;
    size_t off;
    if (seg < 2)      { s = hs; off = i; }
    else if (seg == 2){ s = wq; off = i - 2 * (size_t)SEG; }
    else if (seg == 3){ s = wk; off = i - 3 * (size_t)SEG; }
    else if (seg == 4){ s = wv; off = i - 4 * (size_t)SEG; }
    else              { s = wo; off = i - 5 * (size_t)SEG; }
    f32x4 lo = *(const f32x4*)(s + off);
    f32x4 hi = *(const f32x4*)(s + off + 4);
    short v[8];
#pragma unroll
    for (int j = 0; j < 4; ++j) { v[j] = f2bf(lo[j]); v[4 + j] = f2bf(hi[j]); }
    *(bf16x8*)(dst + i) = *(bf16x8*)v;
}

// ---------------------------------------------------------------------------
// GEMM: C[M][N] = A[M][K] * W[N][K]^T, bf16 (m97 structure).
// ---------------------------------------------------------------------------
template<int MODE>
__global__ __launch_bounds__(256, 4)
void gemm_bt(const short* A, const short* W0, const short* W1, const short* W2,
             short* Oq, short* Ok, short* Ov, float* Of)
{
    __shared__ short smem[2 * 128 * 64];
    short* As = smem;
    short* Bs = smem + 128 * 64;

    const int tid  = threadIdx.x;
    const int lane = tid & 63;
    const int wv   = tid >> 6;
    const int wr   = wv >> 1, wc = wv & 1;
    const int fr   = lane & 15, fg = lane >> 4;

    const int mt = blockIdx.x;
    int nt = blockIdx.y;
    const short* W = W0;
    short* Ob = Oq;
    int osel = 0;
    if (MODE == 0) {
        osel = nt >> 4; nt &= 15;
        W  = (osel == 0) ? W0 : (osel == 1) ? W1 : W2;
        Ob = (osel == 0) ? Oq : (osel == 1) ? Ok : Ov;
    }
    const int row0 = mt * 128, col0 = nt * 128;
    const int sr = tid >> 3, sb = tid & 7;

    f32x4 acc[4][4];
#pragma unroll
    for (int m = 0; m < 4; ++m)
#pragma unroll
        for (int n = 0; n < 4; ++n) acc[m][n] = (f32x4){0.f, 0.f, 0.f, 0.f};

    for (int k0 = 0; k0 < HIDDEN; k0 += 64) {
        __syncthreads();
#pragma unroll
        for (int it = 0; it < 4; ++it) {
            int r = it * 32 + sr;
            gload16(A + (size_t)(row0 + r) * HIDDEN + k0 + ((sb ^ (r & 7)) * 8),
                    (char*)As + (it * 256 + wv * 64) * 16);
        }
#pragma unroll
        for (int it = 0; it < 4; ++it) {
            int r = it * 32 + sr;
            gload16(W + (size_t)(col0 + r) * HIDDEN + k0 + ((sb ^ (r & 7)) * 8),
                    (char*)Bs + (it * 256 + wv * 64) * 16);
        }
        __syncthreads();
#pragma unroll
        for (int ks = 0; ks < 2; ++ks) {
            bf16x8 a[4], b[4];
#pragma unroll
            for (int m = 0; m < 4; ++m) {
                int r = wr * 64 + m * 16 + fr;
                a[m] = *(const bf16x8*)&As[r * 64 + (((ks * 4 + fg) ^ (r & 7)) * 8)];
            }
#pragma unroll
            for (int n = 0; n < 4; ++n) {
                int r = wc * 64 + n * 16 + fr;
                b[n] = *(const bf16x8*)&Bs[r * 64 + (((ks * 4 + fg) ^ (r & 7)) * 8)];
            }
#pragma unroll
            for (int m = 0; m < 4; ++m)
#pragma unroll
                for (int n = 0; n < 4; ++n)
                    acc[m][n] = mfma16(a[m], b[n], acc[m][n]);
        }
    }

    if (MODE == 0 && osel == 2) {
        __syncthreads();
#pragma unroll
        for (int m = 0; m < 4; ++m)
#pragma unroll
            for (int j = 0; j < 4; ++j) {
                int row = wr * 64 + m * 16 + fg * 4 + j;
#pragma unroll
                for (int n = 0; n < 4; ++n) {
                    int col = wc * 64 + n * 16 + fr;
                    smem[col * 128 + (((row >> 3) ^ (col & 15)) * 8) + (row & 7)] =
                        f2bf(acc[m][n][j]);
                }
            }
        __syncthreads();
        const int b_ = row0 >> 11;
        const int bh = b_ * NH + nt;
        const int s0 = row0 & (S_LEN - 1);
#pragma unroll
        for (int it = 0; it < 8; ++it) {
            int c = it * 256 + tid;
            int d = c >> 4, sbk = c & 15;
            bf16x8 vv = *(const bf16x8*)&smem[d * 128 + ((sbk ^ (d & 15)) * 8)];
            *(bf16x8*)(Ov + ((size_t)bh * HD + d) * S_LEN + s0 + sbk * 8) = vv;
        }
    } else {
#pragma unroll
        for (int m = 0; m < 4; ++m)
#pragma unroll
            for (int j = 0; j < 4; ++j) {
                int mrow = row0 + wr * 64 + m * 16 + fg * 4 + j;
#pragma unroll
                for (int n = 0; n < 4; ++n) {
                    int col = col0 + wc * 64 + n * 16 + fr;
                    float val = acc[m][n][j];
                    if (MODE == 0) {
                        int b_ = mrow >> 11, s = mrow & (S_LEN - 1);
                        int h = col >> 7, d = col & (HD - 1);
                        Ob[((size_t)(b_ * NH + h) * S_LEN + s) * HD + d] = f2bf(val);
                    } else {
                        Of[(size_t)mrow * HIDDEN + col] = val;
                    }
                }
            }
    }
}

// ---------------------------------------------------------------------------
__global__ void rope_table_k(float* tab)
{
    int i = blockIdx.x * 256 + threadIdx.x;
    if (i >= S_LEN * 64) return;
    int s = i >> 6, d = i & 63;
    float inv = 1.0f / powf(10000.0f, (float)d * (1.0f / 64.0f));
    float ang = (float)s * inv;
    tab[2 * i]     = cosf(ang);
    tab[2 * i + 1] = sinf(ang);
}

__global__ void rope_apply_k(short* Q, short* K, const float* tab)
{
    int i = blockIdx.x * 256 + threadIdx.x;
    int d8 = i & 7;
    int s  = (i >> 3) & (S_LEN - 1);
    int bh = i >> 14;
    size_t base = ((size_t)bh * S_LEN + s) * HD + d8 * 8;
    const float* tp = tab + (s * 64 + d8 * 8) * 2;
    f32x4 t[4];
#pragma unroll
    for (int j = 0; j < 4; ++j) t[j] = *(const f32x4*)(tp + j * 4);

    bf16x8 q1 = *(bf16x8*)(Q + base), q2 = *(bf16x8*)(Q + base + 64);
    bf16x8 k1 = *(bf16x8*)(K + base), k2 = *(bf16x8*)(K + base + 64);
    short oq1[8], oq2[8], ok1[8], ok2[8];
    const float qs = 0.08838834764831845f;
#pragma unroll
    for (int j = 0; j < 8; ++j) {
        float c  = t[j >> 1][(j & 1) * 2];
        float sn = t[j >> 1][(j & 1) * 2 + 1];
        float a1 = bf2f(q1[j]), a2 = bf2f(q2[j]);
        oq1[j] = f2bf((a1 * c - a2 * sn) * qs);
        oq2[j] = f2bf((a2 * c + a1 * sn) * qs);
        float b1 = bf2f(k1[j]), b2 = bf2f(k2[j]);
        ok1[j] = f2bf(b1 * c - b2 * sn);
        ok2[j] = f2bf(b2 * c + b1 * sn);
    }
    *(bf16x8*)(Q + base)      = *(bf16x8*)oq1;
    *(bf16x8*)(Q + base + 64) = *(bf16x8*)oq2;
    *(bf16x8*)(K + base)      = *(bf16x8*)ok1;
    *(bf16x8*)(K + base + 64) = *(bf16x8*)ok2;
}

// ---------------------------------------------------------------------------
// Causal flash attention. Grid: (32 bh, 16). qt = 15 - blockIdx.y (long first).
// 4 waves x 32 q-rows (QBLK 128). KVBLK 64, double-buffered K and V in LDS.
// K [bh][s][d]; V [bh][d][s] (transposed).
// ---------------------------------------------------------------------------
__global__ __launch_bounds__(256, 1)
void attn_k(const short* Q, const short* K, const short* Vt, short* AO)
{
    __shared__ short Ks[2][64 * 128];   // 32 KB: row k (64) x 128 d; blk^(r&15)
    __shared__ short Vs[2][128 * 64];   // 32 KB: row d (128) x 64 s; blk^(d&7)
    __shared__ short Ps[4][32 * 64];    // 16 KB: per-wave P; blk^(ql&7)

    const int tid = threadIdx.x, lane = tid & 63, wv = tid >> 6;
    const int fr = lane & 15, fg = lane >> 4;
    const int bh = blockIdx.x;
    const int qt = 15 - blockIdx.y;     // long blocks dispatch first

    const short* Qb = Q  + (size_t)bh * S_LEN * HD;
    const short* Kb = K  + (size_t)bh * S_LEN * HD;
    const short* Vb = Vt + (size_t)bh * HD * S_LEN;
    const int qbase = qt * 128 + wv * 32;

    bf16x8 qf[2][4];
#pragma unroll
    for (int mi = 0; mi < 2; ++mi)
#pragma unroll
        for (int ks = 0; ks < 4; ++ks)
            qf[mi][ks] = *(const bf16x8*)(Qb + (size_t)(qbase + mi * 16 + fr) * HD
                                          + ks * 32 + fg * 8);

    f32x4 o[2][8];
    float mrun[2][4], lrun[2][4];
#pragma unroll
    for (int mi = 0; mi < 2; ++mi) {
#pragma unroll
        for (int nd = 0; nd < 8; ++nd) o[mi][nd] = (f32x4){0.f, 0.f, 0.f, 0.f};
#pragma unroll
        for (int j = 0; j < 4; ++j) { mrun[mi][j] = -1e30f; lrun[mi][j] = 0.f; }
    }

    // staging helper coords: K tile = 64x128 -> 1024 chunks of 16B, 4/thread.
    // V tile = 128x64 -> 1024 chunks, 4/thread.
    const int krs = tid >> 2, kbs = tid & 3;   // unused granularity helper
    (void)krs; (void)kbs;

    const int ntiles = (qt + 1) * 2;

#define STAGE(t, bufi)                                                          \
    do {                                                                        \
        const int kb_ = (t) * 64;                                               \
        _Pragma("unroll")                                                       \
        for (int i_ = 0; i_ < 4; ++i_) {                                        \
            int c_ = i_ * 256 + tid;                                            \
            int r_ = c_ >> 4, b_ = c_ & 15;                                     \
            gload16(Kb + (size_t)(kb_ + r_) * HD + ((b_ ^ (r_ & 15)) * 8),      \
                    (char*)&Ks[bufi][0] + c_ * 16);                             \
        }                                                                       \
        _Pragma("unroll")                                                       \
        for (int i_ = 0; i_ < 4; ++i_) {                                        \
            int c_ = i_ * 256 + tid;                                            \
            int r_ = c_ >> 3, b_ = c_ & 7;                                      \
            gload16(Vb + (size_t)r_ * S_LEN + kb_ + ((b_ ^ (r_ & 7)) * 8),      \
                    (char*)&Vs[bufi][0] + c_ * 16);                             \
        }                                                                       \
    } while (0)

    STAGE(0, 0);

    for (int t = 0; t < ntiles; ++t) {
        const int buf = t & 1;
        __syncthreads();                        // drains vmcnt -> buf ready
        if (t + 1 < ntiles) STAGE(t + 1, buf ^ 1);
        const int kb = t * 64;

        if (kb <= qbase + 31) {                 // wave-uniform causal skip
            // ---- QK^T: sc[mi][ni] over 64 kv cols ----
            f32x4 sc[2][4];
#pragma unroll
            for (int mi = 0; mi < 2; ++mi)
#pragma unroll
                for (int ni = 0; ni < 4; ++ni) sc[mi][ni] = (f32x4){0.f, 0.f, 0.f, 0.f};
#pragma unroll
            for (int ks = 0; ks < 4; ++ks) {
                bf16x8 kf[4];
#pragma unroll
                for (int ni = 0; ni < 4; ++ni) {
                    int kc = ni * 16 + fr;
                    kf[ni] = *(const bf16x8*)&Ks[buf][kc * 128 + (((ks * 4 + fg) ^ (kc & 15)) * 8)];
                }
#pragma unroll
                for (int mi = 0; mi < 2; ++mi)
#pragma unroll
                    for (int ni = 0; ni < 4; ++ni)
                        sc[mi][ni] = mfma16(qf[mi][ks], kf[ni], sc[mi][ni]);
            }
            const bool need_mask = (kb + 63 > qbase);
            // ---- online softmax ----
#pragma unroll
            for (int mi = 0; mi < 2; ++mi) {
#pragma unroll
                for (int j = 0; j < 4; ++j) {
                    int qrow = qbase + mi * 16 + fg * 4 + j;
                    if (need_mask) {
#pragma unroll
                        for (int ni = 0; ni < 4; ++ni) {
                            int kcol = kb + ni * 16 + fr;
                            if (kcol > qrow) sc[mi][ni][j] = -1e30f;
                        }
                    }
                    float mx = fmaxf(fmaxf(sc[mi][0][j], sc[mi][1][j]),
                                     fmaxf(sc[mi][2][j], sc[mi][3][j]));
                    mx = fmaxf(mx, __shfl_xor(mx, 1));
                    mx = fmaxf(mx, __shfl_xor(mx, 2));
                    mx = fmaxf(mx, __shfl_xor(mx, 4));
                    mx = fmaxf(mx, __shfl_xor(mx, 8));
                    if (mx > mrun[mi][j]) {     // rescale only on new max
                        float scale = __expf(mrun[mi][j] - mx);
                        mrun[mi][j] = mx;
                        lrun[mi][j] *= scale;
#pragma unroll
                        for (int nd = 0; nd < 8; ++nd) o[mi][nd][j] *= scale;
                    }
                    float m_ = mrun[mi][j];
                    float rs = 0.f;
                    int ql = mi * 16 + fg * 4 + j;
#pragma unroll
                    for (int ni = 0; ni < 4; ++ni) {
                        float p = __expf(sc[mi][ni][j] - m_);
                        rs += p;
                        int kl = ni * 16 + fr;
                        Ps[wv][ql * 64 + (((kl >> 3) ^ (ql & 7)) * 8) + (kl & 7)] =
                            f2bf(p);
                    }
                    rs += __shfl_xor(rs, 1);
                    rs += __shfl_xor(rs, 2);
                    rs += __shfl_xor(rs, 4);
                    rs += __shfl_xor(rs, 8);
                    lrun[mi][j] += rs;
                }
            }
            asm volatile("s_waitcnt lgkmcnt(0)" ::: "memory");
            // ---- P @ V ----
            bf16x8 pa[2][2];
#pragma unroll
            for (int mi = 0; mi < 2; ++mi) {
                int ql = mi * 16 + fr;
#pragma unroll
                for (int ks = 0; ks < 2; ++ks)
                    pa[mi][ks] = *(const bf16x8*)&Ps[wv][ql * 64 + (((ks * 4 + fg) ^ (ql & 7)) * 8)];
            }
#pragma unroll
            for (int nd = 0; nd < 8; ++nd) {
                int d = nd * 16 + fr;
#pragma unroll
                for (int ks = 0; ks < 2; ++ks) {
                    bf16x8 vf = *(const bf16x8*)&Vs[buf][d * 64 + (((ks * 4 + fg) ^ (d & 7)) * 8)];
#pragma unroll
                    for (int mi = 0; mi < 2; ++mi)
                        o[mi][nd] = mfma16(pa[mi][ks], vf, o[mi][nd]);
                }
            }
        }
    }
#undef STAGE

    const int b_ = bh >> 4, h = bh & 15;
#pragma unroll
    for (int mi = 0; mi < 2; ++mi)
#pragma unroll
        for (int j = 0; j < 4; ++j) {
            float inv = 1.0f / lrun[mi][j];
            int srow = qbase + mi * 16 + fg * 4 + j;
#pragma unroll
            for (int nd = 0; nd < 8; ++nd) {
                int col = h * HD + nd * 16 + fr;
                AO[((size_t)b_ * S_LEN + srow) * HIDDEN + col] =
                    f2bf(o[mi][nd][j] * inv);
            }
        }
}

// ---------------------------------------------------------------------------
extern "C" void kernel_launch(void* const* d_in, const int* in_sizes, int n_in,
                              void* d_out, int out_size, void* d_ws, size_t ws_size,
                              hipStream_t stream)
{
    const float* hs = (const float*)d_in[0];
    const float* wq = (const float*)d_in[1];
    const float* wk = (const float*)d_in[2];
    const float* wvp = (const float*)d_in[3];
    const float* wo = (const float*)d_in[4];
    float* out = (float*)d_out;

    char* ws = (char*)d_ws;
    short* CB  = (short*)ws;
    short* Hb  = CB;
    short* Wqb = CB + 2 * (size_t)SEG;
    short* Wkb = CB + 3 * (size_t)SEG;
    short* Wvb = CB + 4 * (size_t)SEG;
    short* Wob = CB + 5 * (size_t)SEG;
    short* Qb  = (short*)(ws + 50331648);
    short* Kb  = (short*)(ws + 67108864);
    short* Vb  = (short*)(ws + 83886080);   // [bh][d][s]
    short* AO  = Hb;                         // alias: hidden dead after gemm<0>
    float* tab = (float*)(ws + 100663296);

    cast_k<<<dim3(12288), dim3(256), 0, stream>>>(hs, wq, wk, wvp, wo, CB);
    rope_table_k<<<dim3(512), dim3(256), 0, stream>>>(tab);
    gemm_bt<0><<<dim3(32, 48), dim3(256), 0, stream>>>(
        Hb, Wqb, Wkb, Wvb, Qb, Kb, Vb, nullptr);
    rope_apply_k<<<dim3(2048), dim3(256), 0, stream>>>(Qb, Kb, tab);
    attn_k<<<dim3(32, 16), dim3(256), 0, stream>>>(Qb, Kb, Vb, AO);
    gemm_bt<1><<<dim3(32, 16), dim3(256), 0, stream>>>(
        AO, Wob, nullptr, nullptr, nullptr, nullptr, nullptr, out);
}